// Round 1
// baseline (1385.045 us; speedup 1.0000x reference)
//
#include <hip/hip_runtime.h>
#include <float.h>

#define B_     64
#define TTXT   64
#define TIMG   197
#define DDIM   768
#define MT     63      // tf rows (text tokens 1..63)
#define NI     196     // imf rows (image tokens 1..196)
#define DC     16
#define MARGIN_ 0.5f
#define EPS_    1e-6f

// ws layout (ints): nv[64] | vidx[64][63]
__global__ __launch_bounds__(64) void prep_kernel(const int* __restrict__ pm,
                                                  int* __restrict__ wsi,
                                                  float* __restrict__ out) {
    int x = threadIdx.x;
    if (x == 0) out[0] = 0.f;
    if (x >= B_) return;
    const int* row = pm + x * TTXT;
    // eos = index of last zero (argmax of cumsum of zeros), 0 if no zeros
    int lastz = -1;
    for (int t = 0; t < TTXT; ++t) if (row[t] == 0) lastz = t;
    int eos = (lastz >= 0) ? lastz : 0;
    // valid text-row tt = t-1 where effective pm[t]==0 (pm[eos] forced to 1)
    int nv = 0;
    int* vv = wsi + 64 + x * MT;
    for (int t = 1; t < TTXT; ++t) {
        int v = row[t];
        if (t == eos) v = 1;
        if (v == 0) vv[nv++] = t - 1;
    }
    wsi[x] = nv;
}

// One block per (x,y). Computes t2i[x,y], i2t[x,y], margins, atomicAdd into loss.
__global__ __launch_bounds__(256) void sim_kernel(const float* __restrict__ img,
                                                  const float* __restrict__ txt,
                                                  const int* __restrict__ tgt,
                                                  const int* __restrict__ wsi,
                                                  float* __restrict__ out)
{
    const int bid = blockIdx.x;
    const int x = bid & 63;        // x fastest: 64 consecutive blocks share imf[y]
    const int y = bid >> 6;
    const int tid = threadIdx.x;
    const int w = tid >> 6;        // wave id: owns t-rows {w, w+4, w+8, ...}
    const int c = tid & 63;        // lane: owns image cols {c, c+64, c+128, c+192}

    __shared__ float sA[MT][DC];          // compacted valid text rows, K-chunk
    __shared__ float sB[NI][DC + 4];      // image rows, K-chunk (+4 pad: conflict-free b128)
    __shared__ float red[4 * 256];        // cross-wave col-max
    __shared__ float wred[8];             // [0..3] row-sum per wave, [4..7] col-sum per wave

    const int nv = wsi[x];
    const int* vv = wsi + 64 + x * MT;

    const float* timg = img + (size_t)y * TIMG * DDIM + DDIM;   // skip image token 0
    const float* ttxt = txt + (size_t)x * TTXT * DDIM + DDIM;   // skip text token 0

    float acc[16][4];
    #pragma unroll
    for (int v = 0; v < 16; ++v)
        #pragma unroll
        for (int u = 0; u < 4; ++u) acc[v][u] = 0.f;

    for (int dc = 0; dc < DDIM; dc += DC) {
        __syncthreads();   // previous-iter LDS readers done before overwrite
        // stage B: 196 rows x 16 floats = 784 float4, coalesced-ish (4 float4/row)
        for (int r = tid; r < NI * 4; r += 256) {
            int row = r >> 2, seg = r & 3;
            float4 vsrc = *reinterpret_cast<const float4*>(
                timg + (size_t)row * DDIM + dc + seg * 4);
            *reinterpret_cast<float4*>(&sB[row][seg * 4]) = vsrc;
        }
        // stage A: nv compacted rows x 16 floats
        if (tid < nv * 4) {
            int j = tid >> 2, seg = tid & 3;
            int t = vv[j];
            float4 vsrc = *reinterpret_cast<const float4*>(
                ttxt + (size_t)t * DDIM + dc + seg * 4);
            *reinterpret_cast<float4*>(&sA[j][seg * 4]) = vsrc;
        }
        __syncthreads();
        // compute: per thread 16 t-slots x 4 i's, 4-d sub-chunks via float4
        #pragma unroll
        for (int ds = 0; ds < 4; ++ds) {
            float4 b0 = *reinterpret_cast<const float4*>(&sB[c][ds * 4]);
            float4 b1 = *reinterpret_cast<const float4*>(&sB[c + 64][ds * 4]);
            float4 b2 = *reinterpret_cast<const float4*>(&sB[c + 128][ds * 4]);
            float4 b3 = *reinterpret_cast<const float4*>(&sB[(c + 192 < NI) ? (c + 192) : (NI - 1)][ds * 4]);
            #pragma unroll
            for (int v = 0; v < 16; ++v) {
                int t = 4 * v + w;
                if (t < nv) {              // wave-uniform: real skip via s_cbranch
                    float4 a = *reinterpret_cast<const float4*>(&sA[t][ds * 4]);
                    acc[v][0] += a.x * b0.x + a.y * b0.y + a.z * b0.z + a.w * b0.w;
                    acc[v][1] += a.x * b1.x + a.y * b1.y + a.z * b1.z + a.w * b1.w;
                    acc[v][2] += a.x * b2.x + a.y * b2.y + a.z * b2.z + a.w * b2.w;
                    acc[v][3] += a.x * b3.x + a.y * b3.y + a.z * b3.z + a.w * b3.w;
                }
            }
        }
    }

    // ---- reductions ----
    float tsum = 0.f;                      // sum over valid t of max_i sim[t,i]
    float cmax[4] = {-FLT_MAX, -FLT_MAX, -FLT_MAX, -FLT_MAX};  // col-max over valid t
    #pragma unroll
    for (int v = 0; v < 16; ++v) {
        int t = 4 * v + w;
        if (t < nv) {
            float r = -FLT_MAX;
            #pragma unroll
            for (int u = 0; u < 4; ++u) {
                int i = c + 64 * u;
                if (i < NI) {
                    float val = acc[v][u];
                    r = fmaxf(r, val);
                    cmax[u] = fmaxf(cmax[u], val);
                }
            }
            #pragma unroll
            for (int off = 1; off < 64; off <<= 1)
                r = fmaxf(r, __shfl_xor(r, off));
            tsum += r;                     // identical across lanes after reduce
        }
    }

    __syncthreads();                       // LDS reuse barrier (red overlaps nothing, but order writes)
    #pragma unroll
    for (int u = 0; u < 4; ++u)
        red[w * 256 + c + 64 * u] = cmax[u];
    if (c == 0) wred[w] = tsum;
    __syncthreads();

    // i2t: per-i max across waves, then block-sum over i<196
    float cm = 0.f;
    if (tid < NI) {
        float m0 = fmaxf(red[tid], red[256 + tid]);
        float m1 = fmaxf(red[512 + tid], red[768 + tid]);
        cm = fmaxf(m0, m1);
    }
    float s = cm;
    #pragma unroll
    for (int off = 1; off < 64; off <<= 1)
        s += __shfl_xor(s, off);
    if (c == 0) wred[4 + w] = s;
    __syncthreads();

    if (tid == 0) {
        float rowsum = wred[0] + wred[1] + wred[2] + wred[3];
        float colsum = wred[4] + wred[5] + wred[6] + wred[7];
        float t2i = rowsum / fmaxf((float)nv, EPS_);
        float i2t = colsum * (1.f / (float)NI);
        int tg = tgt[x * 64 + y];
        float mi = (tg == 1) ? (1.f - i2t) : fmaxf(i2t - MARGIN_, 0.f);
        float mt = (tg == 1) ? (1.f - t2i) : fmaxf(t2i - MARGIN_, 0.f);
        atomicAdd(out, (mi + mt) * (1.f / 8192.f));   // /4096 mean, /2 avg of two losses
    }
}

extern "C" void kernel_launch(void* const* d_in, const int* in_sizes, int n_in,
                              void* d_out, int out_size, void* d_ws, size_t ws_size,
                              hipStream_t stream) {
    const float* img = (const float*)d_in[0];   // image_features (64,197,768) f32
    const float* txt = (const float*)d_in[1];   // text_features  (64,64,768)  f32
    const int*   pm  = (const int*)d_in[2];     // padding_mask   (64,64)      i32
    const int*   tgt = (const int*)d_in[3];     // target         (64,64)      i32
    float* out = (float*)d_out;
    int*   wsi = (int*)d_ws;

    hipLaunchKernelGGL(prep_kernel, dim3(1), dim3(64), 0, stream, pm, wsi, out);
    hipLaunchKernelGGL(sim_kernel, dim3(4096), dim3(256), 0, stream,
                       img, txt, tgt, wsi, out);
}

// Round 3
// 485.170 us; speedup vs baseline: 2.8548x; 2.8548x over previous
//
#include <hip/hip_runtime.h>
#include <float.h>
#include <stdint.h>

#define B_      64
#define TTXT    64
#define TIMG    197
#define DDIM    768
#define MT      63
#define NI      196
#define NPAD    224
#define DC      16
#define MARGIN_ 0.5f
#define EPS_    1e-6f

// ---- fast-path ws byte offsets ----
#define META_OFF   0u          // int meta[16]; meta[0] = R
#define NV_OFF     64u         // int nv[64]
#define ROWSRC_OFF 320u        // int rowsrc[4096] (f32-element offset into txt)
#define ROWX_OFF   16704u      // int rowx[4096]
#define T2I_OFF    33088u      // float t2i_sum[4096]
#define I2T_OFF    49472u      // uint i2t_part[64*64*196] (monotone-mapped f32)
#define AH_OFF     3260736u    // f16 Ah[4096][768]
#define AL_OFF     9552192u    // f16 Al[4096][768]
#define BH_OFF     15843648u   // f16 Bh[64][224][768]
#define BL_OFF     37863744u   // f16 Bl[64][224][768]
#define WS_NEEDED  59883840u   // ~57.1 MiB

typedef _Float16 f16x8 __attribute__((ext_vector_type(8)));
typedef float    f32x4 __attribute__((ext_vector_type(4)));

__device__ __forceinline__ unsigned mono_map(float v) {
    unsigned b = __float_as_uint(v);
    return (b & 0x80000000u) ? ~b : (b | 0x80000000u);
}
__device__ __forceinline__ float mono_unmap(unsigned u) {
    unsigned b = (u & 0x80000000u) ? (u & 0x7fffffffu) : ~u;
    return __uint_as_float(b);
}

// ================= FAST PATH (f16 hi/lo split MFMA) =================

__global__ void init_kernel(char* __restrict__ ws, float* __restrict__ out) {
    unsigned g = blockIdx.x * 256u + threadIdx.x;
    if (g < 802816u) ((unsigned*)(ws + I2T_OFF))[g] = 0x00800000u;  // mono(-FLT_MAX)
    if (g < 4096u)   ((float*)(ws + T2I_OFF))[g] = 0.f;
    if (g == 0u)     out[0] = 0.f;
}

__global__ __launch_bounds__(64) void prep_kernel(const int* __restrict__ pm,
                                                  char* __restrict__ ws) {
    int x = threadIdx.x;
    int* meta   = (int*)(ws + META_OFF);
    int* nv     = (int*)(ws + NV_OFF);
    int* rowsrc = (int*)(ws + ROWSRC_OFF);
    int* rowx   = (int*)(ws + ROWX_OFF);
    const int* row = pm + x * TTXT;
    int lastz = -1;
    for (int t = 0; t < TTXT; ++t) if (row[t] == 0) lastz = t;
    int eos = (lastz >= 0) ? lastz : 0;
    int cnt = 0; int loc[63];
    for (int t = 1; t < TTXT; ++t) {
        int v = row[t]; if (t == eos) v = 1;
        if (v == 0) loc[cnt++] = t;
    }
    int s = cnt;                         // inclusive prefix over the wave
    for (int d = 1; d < 64; d <<= 1) { int o = __shfl_up(s, d); if (x >= d) s += o; }
    int off = s - cnt;
    for (int j = 0; j < cnt; ++j) {
        rowsrc[off + j] = (x * TTXT + loc[j]) * DDIM;
        rowx[off + j] = x;
    }
    nv[x] = cnt;
    if (x == 63) meta[0] = off + cnt;    // R
}

__global__ __launch_bounds__(128) void convA_kernel(const float* __restrict__ txt,
                                                    char* __restrict__ ws) {
    int r = blockIdx.x, t = threadIdx.x;
    if (t >= 96) return;
    const int R = *(const int*)(ws + META_OFF);
    f16x8 hv = 0, lv = 0;
    if (r < R) {
        const int* rowsrc = (const int*)(ws + ROWSRC_OFF);
        const float* src = txt + rowsrc[r] + t * 8;
        float4 f0 = ((const float4*)src)[0];
        float4 f1 = ((const float4*)src)[1];
        float fv[8] = {f0.x, f0.y, f0.z, f0.w, f1.x, f1.y, f1.z, f1.w};
        #pragma unroll
        for (int j = 0; j < 8; ++j) {
            float fx = fv[j];
            _Float16 hf = (_Float16)fx;
            hv[j] = hf;
            lv[j] = (_Float16)(fx - (float)hf);
        }
    }
    size_t eo = ((size_t)r * DDIM + t * 8) * 2;
    *(f16x8*)(ws + AH_OFF + eo) = hv;
    *(f16x8*)(ws + AL_OFF + eo) = lv;
}

__global__ __launch_bounds__(256) void convB_kernel(const float* __restrict__ img,
                                                    char* __restrict__ ws) {
    unsigned gid = blockIdx.x * 256u + threadIdx.x;   // 1,376,256 tasks
    int sl = gid % 96, rr = gid / 96;
    int y = rr / NPAD, i = rr % NPAD;
    f16x8 hv = 0, lv = 0;
    if (i < NI) {
        const float* src = img + ((size_t)(y * TIMG + i + 1) * DDIM + sl * 8);
        float4 f0 = ((const float4*)src)[0];
        float4 f1 = ((const float4*)src)[1];
        float fv[8] = {f0.x, f0.y, f0.z, f0.w, f1.x, f1.y, f1.z, f1.w};
        #pragma unroll
        for (int j = 0; j < 8; ++j) {
            float fx = fv[j];
            _Float16 hf = (_Float16)fx;
            hv[j] = hf;
            lv[j] = (_Float16)(fx - (float)hf);
        }
    }
    size_t eo = ((size_t)rr * DDIM + sl * 8) * 2;
    *(f16x8*)(ws + BH_OFF + eo) = hv;
    *(f16x8*)(ws + BL_OFF + eo) = lv;
}

// grid 2048 = 64 y * 32 m-tiles; block 256 (4 waves, 2x2 over M=128 x N=224)
__global__ __launch_bounds__(256, 2) void gemm_kernel(char* __restrict__ ws) {
    const int bid = blockIdx.x;
    const int y   = bid >> 5;
    const int mt0 = bid & 31;
    const int R = *(const int*)(ws + META_OFF);
    const int m_base = mt0 * 128;
    if (m_base >= R) return;

    const int tid = threadIdx.x;
    const int wid = tid >> 6, lane = tid & 63;
    const int c = lane & 15, g = lane >> 4;
    const int wm = wid >> 1, wn = wid & 1;

    __shared__ __align__(16) unsigned char lds[45056];   // A 16K + B 28K

    const char* Ah = ws + AH_OFF;
    const char* Al = ws + AL_OFF;
    const char* Bh = ws + BH_OFF;
    const char* Bl = ws + BL_OFF;

    f32x4 acc[4][7];
    #pragma unroll
    for (int mt = 0; mt < 4; ++mt)
        #pragma unroll
        for (int nt = 0; nt < 7; ++nt) acc[mt][nt] = 0.f;

    // staging: A 1024 slots (4/thread), B 1792 slots (7/thread); 16B slots
    int awr[4], aoff[4];
    #pragma unroll
    for (int i = 0; i < 4; ++i) {
        int s = tid + 256 * i, ro = s >> 3, sl = s & 7;
        awr[i]  = ro * 128 + ((sl ^ (ro & 7)) << 4);              // swizzled LDS byte
        aoff[i] = (m_base + ro) * DDIM + sl * 8;                  // f16-elem offset
    }
    int bwr[7], boff[7];
    #pragma unroll
    for (int i = 0; i < 7; ++i) {
        int s = tid + 256 * i, ro = s >> 3, sl = s & 7;
        bwr[i]  = 16384 + ro * 128 + ((sl ^ (ro & 7)) << 4);
        boff[i] = (y * NPAD + ro) * DDIM + sl * 8;
    }

    const int ar0 = (wm * 64 + c) * 128;          // A frag row base (bytes)
    const int bq  = 16384 + (wn * 112 + c) * 128; // B frag row base (bytes)
    const int swz = c & 7;

    for (int p = 0; p < 3; ++p) {                 // hi*hi, hi*lo, lo*hi
        const char* Asrc = (p < 2) ? Ah : Al;
        const char* Bsrc = (p == 1) ? Bl : Bh;
        for (int kc = 0; kc < 12; ++kc) {
            const int k0 = kc * 64;
            __syncthreads();                      // prev compute done
            uint4 va[4], vb[7];
            #pragma unroll
            for (int i = 0; i < 4; ++i) va[i] = *(const uint4*)(Asrc + (size_t)(aoff[i] + k0) * 2);
            #pragma unroll
            for (int i = 0; i < 7; ++i) vb[i] = *(const uint4*)(Bsrc + (size_t)(boff[i] + k0) * 2);
            #pragma unroll
            for (int i = 0; i < 4; ++i) *(uint4*)(lds + awr[i]) = va[i];
            #pragma unroll
            for (int i = 0; i < 7; ++i) *(uint4*)(lds + bwr[i]) = vb[i];
            __syncthreads();                      // data ready
            #pragma unroll
            for (int ks = 0; ks < 2; ++ks) {
                const int so = ((ks * 4 + g) ^ swz) << 4;
                f16x8 af[4], bf[7];
                #pragma unroll
                for (int mt = 0; mt < 4; ++mt) af[mt] = *(const f16x8*)(lds + ar0 + mt * 2048 + so);
                #pragma unroll
                for (int nt = 0; nt < 7; ++nt) bf[nt] = *(const f16x8*)(lds + bq + nt * 2048 + so);
                #pragma unroll
                for (int mt = 0; mt < 4; ++mt)
                    #pragma unroll
                    for (int nt = 0; nt < 7; ++nt)
                        acc[mt][nt] = __builtin_amdgcn_mfma_f32_16x16x32_f16(
                            af[mt], bf[nt], acc[mt][nt], 0, 0, 0);
            }
        }
    }

    // ---- epilogue ----
    __syncthreads();
    float* rowmax2 = (float*)lds;            // [2][128]
    int*   rowxl   = (int*)(lds + 1024);     // [128]
    const int* rowx = (const int*)(ws + ROWX_OFF);
    if (tid < 128) {
        int gr = m_base + tid;
        rowxl[tid] = (gr < R) ? rowx[gr] : -1;
    }
    // row-max over i<196 (t2i); D layout: m = wm*64+mt*16+g*4+r, n = wn*112+nt*16+c
    #pragma unroll
    for (int mt = 0; mt < 4; ++mt) {
        #pragma unroll
        for (int r = 0; r < 4; ++r) {
            float v = -FLT_MAX;
            #pragma unroll
            for (int nt = 0; nt < 7; ++nt) {
                int n = wn * 112 + nt * 16 + c;
                if (n < NI) v = fmaxf(v, acc[mt][nt][r]);
            }
            #pragma unroll
            for (int d = 1; d < 16; d <<= 1) v = fmaxf(v, __shfl_xor(v, d));
            if (c == 0) rowmax2[wn * 128 + wm * 64 + mt * 16 + g * 4 + r] = v;
        }
    }
    __syncthreads();
    if (tid < 128) {
        int gr = m_base + tid;
        if (gr < R) {
            float rm = fmaxf(rowmax2[tid], rowmax2[128 + tid]);
            atomicAdd((float*)(ws + T2I_OFF) + rowxl[tid] * 64 + y, rm);
        }
    }
    // col-max per x-segment (i2t) via run-combined atomicMax
    int xr[4][4];
    #pragma unroll
    for (int mt = 0; mt < 4; ++mt)
        #pragma unroll
        for (int r = 0; r < 4; ++r)
            xr[mt][r] = rowxl[wm * 64 + mt * 16 + g * 4 + r];

    unsigned* i2t = (unsigned*)(ws + I2T_OFF);
    #pragma unroll
    for (int nt = 0; nt < 7; ++nt) {
        int n = wn * 112 + nt * 16 + c;
        if (n >= NI) continue;
        int curx = -1; float curm = 0.f;
        #pragma unroll
        for (int mt = 0; mt < 4; ++mt) {
            #pragma unroll
            for (int r = 0; r < 4; ++r) {
                int xv = xr[mt][r];
                float v = acc[mt][nt][r];
                if (xv != curx) {
                    if (curx >= 0)
                        atomicMax(&i2t[(size_t)(curx * 64 + y) * NI + n], mono_map(curm));
                    curx = xv; curm = v;
                } else {
                    curm = fmaxf(curm, v);
                }
            }
        }
        if (curx >= 0)
            atomicMax(&i2t[(size_t)(curx * 64 + y) * NI + n], mono_map(curm));
    }
}

__global__ __launch_bounds__(256) void fin_kernel(const int* __restrict__ tgt,
                                                  char* __restrict__ ws,
                                                  float* __restrict__ out) {
    int w = blockIdx.x * 4 + (threadIdx.x >> 6);      // (x,y) pair, w = x*64+y
    int lane = threadIdx.x & 63;
    int x = w >> 6;
    const unsigned* iv = (const unsigned*)(ws + I2T_OFF) + (size_t)w * NI;
    float s = mono_unmap(iv[lane]) + mono_unmap(iv[64 + lane]) + mono_unmap(iv[128 + lane]);
    if (lane < 4) s += mono_unmap(iv[192 + lane]);
    #pragma unroll
    for (int d = 1; d < 64; d <<= 1) s += __shfl_xor(s, d);
    if (lane == 0) {
        float i2tv = s * (1.f / (float)NI);
        float t2is = ((const float*)(ws + T2I_OFF))[w];
        int   nvx  = ((const int*)(ws + NV_OFF))[x];
        float t2iv = t2is / fmaxf((float)nvx, EPS_);
        int tg = tgt[w];
        float mi  = (tg == 1) ? (1.f - i2tv) : fmaxf(i2tv - MARGIN_, 0.f);
        float mtv = (tg == 1) ? (1.f - t2iv) : fmaxf(t2iv - MARGIN_, 0.f);
        atomicAdd(out, (mi + mtv) * (1.f / 8192.f));  // /4096 mean, /2 avg
    }
}

// ================= FALLBACK PATH (round-1 f32 VALU, known-correct) =========

__global__ __launch_bounds__(64) void prep0_kernel(const int* __restrict__ pm,
                                                   int* __restrict__ wsi,
                                                   float* __restrict__ out) {
    int x = threadIdx.x;
    if (x == 0) out[0] = 0.f;
    if (x >= B_) return;
    const int* row = pm + x * TTXT;
    int lastz = -1;
    for (int t = 0; t < TTXT; ++t) if (row[t] == 0) lastz = t;
    int eos = (lastz >= 0) ? lastz : 0;
    int nv = 0;
    int* vv = wsi + 64 + x * MT;
    for (int t = 1; t < TTXT; ++t) {
        int v = row[t];
        if (t == eos) v = 1;
        if (v == 0) vv[nv++] = t - 1;
    }
    wsi[x] = nv;
}

__global__ __launch_bounds__(256) void sim0_kernel(const float* __restrict__ img,
                                                   const float* __restrict__ txt,
                                                   const int* __restrict__ tgt,
                                                   const int* __restrict__ wsi,
                                                   float* __restrict__ out)
{
    const int bid = blockIdx.x;
    const int x = bid & 63;
    const int y = bid >> 6;
    const int tid = threadIdx.x;
    const int w = tid >> 6;
    const int c = tid & 63;

    __shared__ float sA[MT][DC];
    __shared__ float sB[NI][DC + 4];
    __shared__ float red[4 * 256];
    __shared__ float wred[8];

    const int nv = wsi[x];
    const int* vv = wsi + 64 + x * MT;

    const float* timg = img + (size_t)y * TIMG * DDIM + DDIM;
    const float* ttxt = txt + (size_t)x * TTXT * DDIM + DDIM;

    float acc[16][4];
    #pragma unroll
    for (int v = 0; v < 16; ++v)
        #pragma unroll
        for (int u = 0; u < 4; ++u) acc[v][u] = 0.f;

    for (int dc = 0; dc < DDIM; dc += DC) {
        __syncthreads();
        for (int r = tid; r < NI * 4; r += 256) {
            int row = r >> 2, seg = r & 3;
            float4 vsrc = *reinterpret_cast<const float4*>(
                timg + (size_t)row * DDIM + dc + seg * 4);
            *reinterpret_cast<float4*>(&sB[row][seg * 4]) = vsrc;
        }
        if (tid < nv * 4) {
            int j = tid >> 2, seg = tid & 3;
            int t = vv[j];
            float4 vsrc = *reinterpret_cast<const float4*>(
                ttxt + (size_t)t * DDIM + dc + seg * 4);
            *reinterpret_cast<float4*>(&sA[j][seg * 4]) = vsrc;
        }
        __syncthreads();
        #pragma unroll
        for (int ds = 0; ds < 4; ++ds) {
            float4 b0 = *reinterpret_cast<const float4*>(&sB[c][ds * 4]);
            float4 b1 = *reinterpret_cast<const float4*>(&sB[c + 64][ds * 4]);
            float4 b2 = *reinterpret_cast<const float4*>(&sB[c + 128][ds * 4]);
            float4 b3 = *reinterpret_cast<const float4*>(&sB[(c + 192 < NI) ? (c + 192) : (NI - 1)][ds * 4]);
            #pragma unroll
            for (int v = 0; v < 16; ++v) {
                int t = 4 * v + w;
                if (t < nv) {
                    float4 a = *reinterpret_cast<const float4*>(&sA[t][ds * 4]);
                    acc[v][0] += a.x * b0.x + a.y * b0.y + a.z * b0.z + a.w * b0.w;
                    acc[v][1] += a.x * b1.x + a.y * b1.y + a.z * b1.z + a.w * b1.w;
                    acc[v][2] += a.x * b2.x + a.y * b2.y + a.z * b2.z + a.w * b2.w;
                    acc[v][3] += a.x * b3.x + a.y * b3.y + a.z * b3.z + a.w * b3.w;
                }
            }
        }
    }

    float tsum = 0.f;
    float cmax[4] = {-FLT_MAX, -FLT_MAX, -FLT_MAX, -FLT_MAX};
    #pragma unroll
    for (int v = 0; v < 16; ++v) {
        int t = 4 * v + w;
        if (t < nv) {
            float r = -FLT_MAX;
            #pragma unroll
            for (int u = 0; u < 4; ++u) {
                int i = c + 64 * u;
                if (i < NI) {
                    float val = acc[v][u];
                    r = fmaxf(r, val);
                    cmax[u] = fmaxf(cmax[u], val);
                }
            }
            #pragma unroll
            for (int off = 1; off < 64; off <<= 1)
                r = fmaxf(r, __shfl_xor(r, off));
            tsum += r;
        }
    }

    __syncthreads();
    #pragma unroll
    for (int u = 0; u < 4; ++u)
        red[w * 256 + c + 64 * u] = cmax[u];
    if (c == 0) wred[w] = tsum;
    __syncthreads();

    float cm = 0.f;
    if (tid < NI) {
        float m0 = fmaxf(red[tid], red[256 + tid]);
        float m1 = fmaxf(red[512 + tid], red[768 + tid]);
        cm = fmaxf(m0, m1);
    }
    float s = cm;
    #pragma unroll
    for (int off = 1; off < 64; off <<= 1)
        s += __shfl_xor(s, off);
    if (c == 0) wred[4 + w] = s;
    __syncthreads();

    if (tid == 0) {
        float rowsum = wred[0] + wred[1] + wred[2] + wred[3];
        float colsum = wred[4] + wred[5] + wred[6] + wred[7];
        float t2i = rowsum / fmaxf((float)nv, EPS_);
        float i2t = colsum * (1.f / (float)NI);
        int tg = tgt[x * 64 + y];
        float mi = (tg == 1) ? (1.f - i2t) : fmaxf(i2t - MARGIN_, 0.f);
        float mt = (tg == 1) ? (1.f - t2i) : fmaxf(t2i - MARGIN_, 0.f);
        atomicAdd(out, (mi + mt) * (1.f / 8192.f));
    }
}

// ================= launcher =================

extern "C" void kernel_launch(void* const* d_in, const int* in_sizes, int n_in,
                              void* d_out, int out_size, void* d_ws, size_t ws_size,
                              hipStream_t stream) {
    const float* img = (const float*)d_in[0];   // image_features (64,197,768) f32
    const float* txt = (const float*)d_in[1];   // text_features  (64,64,768)  f32
    const int*   pm  = (const int*)d_in[2];     // padding_mask   (64,64)      i32
    const int*   tgt = (const int*)d_in[3];     // target         (64,64)      i32
    float* out = (float*)d_out;

    if (ws_size >= (size_t)WS_NEEDED) {
        char* wsc = (char*)d_ws;
        hipLaunchKernelGGL(init_kernel,  dim3(3136), dim3(256), 0, stream, wsc, out);
        hipLaunchKernelGGL(prep_kernel,  dim3(1),    dim3(64),  0, stream, pm, wsc);
        hipLaunchKernelGGL(convA_kernel, dim3(4096), dim3(128), 0, stream, txt, wsc);
        hipLaunchKernelGGL(convB_kernel, dim3(5376), dim3(256), 0, stream, img, wsc);
        hipLaunchKernelGGL(gemm_kernel,  dim3(2048), dim3(256), 0, stream, wsc);
        hipLaunchKernelGGL(fin_kernel,   dim3(1024), dim3(256), 0, stream, tgt, wsc, out);
    } else {
        int* wsi = (int*)d_ws;
        hipLaunchKernelGGL(prep0_kernel, dim3(1),    dim3(64),  0, stream, pm, wsi, out);
        hipLaunchKernelGGL(sim0_kernel,  dim3(4096), dim3(256), 0, stream,
                           img, txt, tgt, wsi, out);
    }
}

// Round 4
// 317.738 us; speedup vs baseline: 4.3591x; 1.5270x over previous
//
#include <hip/hip_runtime.h>
#include <float.h>
#include <stdint.h>

#define B_      64
#define TTXT    64
#define TIMG    197
#define DDIM    768
#define MT      63
#define NI      196
#define NPAD    224
#define DC      16
#define MARGIN_ 0.5f
#define EPS_    1e-6f

// ---- ws byte offsets ----
#define META_OFF   0u          // int meta[16]; meta[0] = R
#define NV_OFF     64u         // int nv[64]
#define ROWSRC_OFF 320u        // int rowsrc[4096]
#define ROWX_OFF   16704u      // int rowx[4096]
#define T2I_OFF    33088u      // float t2i_sum[4096]
#define I2T_OFF    49472u      // uint i2t_part[64*64*196]
// A image: [4096 rows][24 chunks][8 slots][16B]  (3072 B per row), swizzle baked
#define AIMG_OFF   3260736u
// B image: [64*224 rows][24 chunks][8 slots][16B]
#define BIMG_OFF   15843648u
#define WS_NEEDED  59883840u

typedef _Float16 f16x8 __attribute__((ext_vector_type(8)));
typedef float    f32x4 __attribute__((ext_vector_type(4)));

__device__ __forceinline__ unsigned mono_map(float v) {
    unsigned b = __float_as_uint(v);
    return (b & 0x80000000u) ? ~b : (b | 0x80000000u);
}
__device__ __forceinline__ float mono_unmap(unsigned u) {
    unsigned b = (u & 0x80000000u) ? (u & 0x7fffffffu) : ~u;
    return __uint_as_float(b);
}

__device__ __forceinline__ void async_ld16(const void* g, void* l) {
    __builtin_amdgcn_global_load_lds((const __attribute__((address_space(1))) void*)g,
                                     (__attribute__((address_space(3))) void*)l,
                                     16, 0, 0);
}

// ================= FAST PATH =================

__global__ __launch_bounds__(64) void prep_kernel(const int* __restrict__ pm,
                                                  char* __restrict__ ws) {
    int x = threadIdx.x;
    int* meta   = (int*)(ws + META_OFF);
    int* nv     = (int*)(ws + NV_OFF);
    int* rowsrc = (int*)(ws + ROWSRC_OFF);
    int* rowx   = (int*)(ws + ROWX_OFF);
    const int* row = pm + x * TTXT;
    int lastz = -1;
    for (int t = 0; t < TTXT; ++t) if (row[t] == 0) lastz = t;
    int eos = (lastz >= 0) ? lastz : 0;
    int cnt = 0; int loc[63];
    for (int t = 1; t < TTXT; ++t) {
        int v = row[t]; if (t == eos) v = 1;
        if (v == 0) loc[cnt++] = t;
    }
    int s = cnt;
    for (int d = 1; d < 64; d <<= 1) { int o = __shfl_up(s, d); if (x >= d) s += o; }
    int off = s - cnt;
    for (int j = 0; j < cnt; ++j) {
        rowsrc[off + j] = (x * TTXT + loc[j]) * DDIM;
        rowx[off + j] = x;
    }
    nv[x] = cnt;
    if (x == 63) meta[0] = off + cnt;    // R
}

// conv: builds swizzled hi/lo chunk images + initializes reduction buffers.
// grid 2513: [0,384) A-image, [384,1728) B-image, [1728,2512) i2t init, 2512 t2i/out
__global__ __launch_bounds__(256) void conv_kernel(const float* __restrict__ img,
                                                   const float* __restrict__ txt,
                                                   char* __restrict__ ws,
                                                   float* __restrict__ out) {
    const int bid = blockIdx.x, tid = threadIdx.x;
    if (bid < 384) {                              // ---- A image (4096 rows x 24 kc)
        int gid = bid * 256 + tid;
        int kc = gid % 24, gr = gid / 24;
        const int R = *(const int*)(ws + META_OFF);
        float f[32];
        if (gr < R) {
            const int* rowsrc = (const int*)(ws + ROWSRC_OFF);
            const float4* s4 = (const float4*)(txt + rowsrc[gr] + kc * 32);
            #pragma unroll
            for (int j = 0; j < 8; ++j) {
                float4 v = s4[j];
                f[4*j] = v.x; f[4*j+1] = v.y; f[4*j+2] = v.z; f[4*j+3] = v.w;
            }
        } else {
            #pragma unroll
            for (int j = 0; j < 32; ++j) f[j] = 0.f;
        }
        char* dst = ws + AIMG_OFF + (size_t)gr * 3072 + kc * 128;
        int rs = gr & 7;
        #pragma unroll
        for (int sp = 0; sp < 8; ++sp) {          // sp = plane*4 + kslot (static)
            f16x8 v;
            #pragma unroll
            for (int j = 0; j < 8; ++j) {
                float fx = f[(sp & 3) * 8 + j];
                _Float16 hh = (_Float16)fx;
                v[j] = (sp & 4) ? (_Float16)(fx - (float)hh) : hh;
            }
            *(f16x8*)(dst + ((sp ^ rs) << 4)) = v;   // inverse-swizzled slot
        }
    } else if (bid < 1728) {                      // ---- B image (64*224 rows x 24 kc)
        int gid = (bid - 384) * 256 + tid;
        int kc = gid % 24, rr = gid / 24;
        int y = rr / NPAD, i = rr % NPAD;
        float f[32];
        if (i < NI) {
            const float4* s4 = (const float4*)(img + (size_t)(y * TIMG + i + 1) * DDIM + kc * 32);
            #pragma unroll
            for (int j = 0; j < 8; ++j) {
                float4 v = s4[j];
                f[4*j] = v.x; f[4*j+1] = v.y; f[4*j+2] = v.z; f[4*j+3] = v.w;
            }
        } else {
            #pragma unroll
            for (int j = 0; j < 32; ++j) f[j] = 0.f;
        }
        char* dst = ws + BIMG_OFF + (size_t)rr * 3072 + kc * 128;
        int rs = i & 7;
        #pragma unroll
        for (int sp = 0; sp < 8; ++sp) {
            f16x8 v;
            #pragma unroll
            for (int j = 0; j < 8; ++j) {
                float fx = f[(sp & 3) * 8 + j];
                _Float16 hh = (_Float16)fx;
                v[j] = (sp & 4) ? (_Float16)(fx - (float)hh) : hh;
            }
            *(f16x8*)(dst + ((sp ^ rs) << 4)) = v;
        }
    } else if (bid < 2512) {                      // ---- i2t init (200704 uint4)
        int gid = (bid - 1728) * 256 + tid;
        uint4 v = make_uint4(0x00800000u, 0x00800000u, 0x00800000u, 0x00800000u);
        ((uint4*)(ws + I2T_OFF))[gid] = v;        // mono(-FLT_MAX)
    } else {                                      // ---- t2i + out init
        uint4 z = make_uint4(0u, 0u, 0u, 0u);
        #pragma unroll
        for (int j = 0; j < 4; ++j)
            ((uint4*)(ws + T2I_OFF))[tid * 4 + j] = z;
        if (tid == 0) out[0] = 0.f;
    }
}

// gemm: grid 1024 = 16 m-tiles(256) x 64 y; 512 threads (8 waves, 4x2 over 256x224)
// merged 3-pass (hh, hl, lh), double-buffered LDS, global_load_lds staging,
// 2-phase pipeline: prefetch chunk k+1 issued before compute of chunk k.
__global__ __launch_bounds__(512, 2) void gemm_kernel(char* __restrict__ ws) {
    const int bid = blockIdx.x;
    const int swz = (bid & 7) * 128 + (bid >> 3);   // XCD-chunked, bijective (1024%8==0)
    const int mt  = swz & 15;                       // mt fastest within XCD chunk
    const int y   = swz >> 4;
    const int R = *(const int*)(ws + META_OFF);
    const int m_base = mt * 256;
    if (m_base >= R) return;

    const int tid = threadIdx.x;
    const int wid = tid >> 6, lane = tid & 63;
    const int c = lane & 15, g = lane >> 4;
    const int wm = wid >> 1, wn = wid & 1;

    __shared__ __align__(16) unsigned char lds[122880];  // 2 x (A 32K + B 28K)

    f32x4 acc[4][7];
    #pragma unroll
    for (int m = 0; m < 4; ++m)
        #pragma unroll
        for (int n = 0; n < 7; ++n) acc[m][n] = 0.f;

    // per-thread global staging addresses (slot u = i*512+tid -> row u>>3, slot u&7)
    const char* Abp = ws + AIMG_OFF + (size_t)m_base * 3072;
    const char* Bbp = ws + BIMG_OFF + (size_t)(y * NPAD) * 3072;
    const char* ga[4]; const char* gb[4];
    #pragma unroll
    for (int i = 0; i < 4; ++i) { int u = i * 512 + tid; ga[i] = Abp + (u >> 3) * 3072 + (u & 7) * 16; }
    #pragma unroll
    for (int i = 0; i < 4; ++i) { int u = i * 512 + tid; gb[i] = Bbp + (u >> 3) * 3072 + (u & 7) * 16; }

    auto STAGE = [&](int buf, int kc) {
        unsigned char* base = lds + buf * 61440;
        const int ko = kc * 128;
        #pragma unroll
        for (int i = 0; i < 4; ++i)
            async_ld16(ga[i] + ko, base + i * 8192 + wid * 1024);
        #pragma unroll
        for (int i = 0; i < 3; ++i)
            async_ld16(gb[i] + ko, base + 32768 + i * 8192 + wid * 1024);
        if (wid < 4)                                 // partial: slots 1536..1791
            async_ld16(gb[3] + ko, base + 32768 + 24576 + wid * 1024);
    };

    // fragment LDS byte offsets (swizzled reads; row stride 128 B = 8 slots)
    int aofh[4], aofl[4], bofh[7], bofl[7];
    #pragma unroll
    for (int m = 0; m < 4; ++m) {
        int r = wm * 64 + m * 16 + c;
        aofh[m] = r * 128 + ((g ^ (r & 7)) << 4);
        aofl[m] = r * 128 + (((4 | g) ^ (r & 7)) << 4);
    }
    #pragma unroll
    for (int n = 0; n < 7; ++n) {
        int i = wn * 112 + n * 16 + c;
        bofh[n] = 32768 + i * 128 + ((g ^ (i & 7)) << 4);
        bofl[n] = 32768 + i * 128 + (((4 | g) ^ (i & 7)) << 4);
    }

    STAGE(0, 0);
    __syncthreads();

    #pragma unroll 2
    for (int kc = 0; kc < 24; ++kc) {
        const int cur = kc & 1;
        if (kc < 23) STAGE(cur ^ 1, kc + 1);         // prefetch next chunk (in flight)
        const unsigned char* Ab = lds + cur * 61440;
        f16x8 ah[4], bh[7];
        #pragma unroll
        for (int m = 0; m < 4; ++m) ah[m] = *(const f16x8*)(Ab + aofh[m]);
        #pragma unroll
        for (int n = 0; n < 7; ++n) bh[n] = *(const f16x8*)(Ab + bofh[n]);
        #pragma unroll
        for (int m = 0; m < 4; ++m)
            #pragma unroll
            for (int n = 0; n < 7; ++n)
                acc[m][n] = __builtin_amdgcn_mfma_f32_16x16x32_f16(ah[m], bh[n], acc[m][n], 0, 0, 0);
        {
            f16x8 bl[7];
            #pragma unroll
            for (int n = 0; n < 7; ++n) bl[n] = *(const f16x8*)(Ab + bofl[n]);
            #pragma unroll
            for (int m = 0; m < 4; ++m)
                #pragma unroll
                for (int n = 0; n < 7; ++n)
                    acc[m][n] = __builtin_amdgcn_mfma_f32_16x16x32_f16(ah[m], bl[n], acc[m][n], 0, 0, 0);
        }
        {
            f16x8 al[4];
            #pragma unroll
            for (int m = 0; m < 4; ++m) al[m] = *(const f16x8*)(Ab + aofl[m]);
            #pragma unroll
            for (int m = 0; m < 4; ++m)
                #pragma unroll
                for (int n = 0; n < 7; ++n)
                    acc[m][n] = __builtin_amdgcn_mfma_f32_16x16x32_f16(al[m], bh[n], acc[m][n], 0, 0, 0);
        }
        __syncthreads();   // all readers done; next iter may overwrite buf cur
    }

    // ---- epilogue ----
    float* rowmax2 = (float*)lds;            // [2][256]
    int*   rowxl   = (int*)(lds + 2048);     // [256]
    const int* rowx = (const int*)(ws + ROWX_OFF);
    if (tid < 256) {
        int gr = m_base + tid;
        rowxl[tid] = (gr < R) ? rowx[gr] : -1;
    }
    // D layout: m = wm*64 + m_i*16 + g*4 + r ; n = wn*112 + n_i*16 + c
    #pragma unroll
    for (int m = 0; m < 4; ++m) {
        #pragma unroll
        for (int r = 0; r < 4; ++r) {
            float v = -FLT_MAX;
            #pragma unroll
            for (int n = 0; n < 7; ++n) {
                int nn = wn * 112 + n * 16 + c;
                if (nn < NI) v = fmaxf(v, acc[m][n][r]);
            }
            #pragma unroll
            for (int d = 1; d < 16; d <<= 1) v = fmaxf(v, __shfl_xor(v, d));
            if (c == 0) rowmax2[wn * 256 + wm * 64 + m * 16 + g * 4 + r] = v;
        }
    }
    __syncthreads();
    if (tid < 256) {
        int gr = m_base + tid;
        if (gr < R) {
            float rm = fmaxf(rowmax2[tid], rowmax2[256 + tid]);
            atomicAdd((float*)(ws + T2I_OFF) + rowxl[tid] * 64 + y, rm);
        }
    }
    int xr[4][4];
    #pragma unroll
    for (int m = 0; m < 4; ++m)
        #pragma unroll
        for (int r = 0; r < 4; ++r)
            xr[m][r] = rowxl[wm * 64 + m * 16 + g * 4 + r];

    unsigned* i2t = (unsigned*)(ws + I2T_OFF);
    #pragma unroll
    for (int n = 0; n < 7; ++n) {
        int nn = wn * 112 + n * 16 + c;
        if (nn >= NI) continue;
        int curx = -1; float curm = 0.f;
        #pragma unroll
        for (int m = 0; m < 4; ++m) {
            #pragma unroll
            for (int r = 0; r < 4; ++r) {
                int xv = xr[m][r];
                float v = acc[m][n][r];
                if (xv != curx) {
                    if (curx >= 0)
                        atomicMax(&i2t[(size_t)(curx * 64 + y) * NI + nn], mono_map(curm));
                    curx = xv; curm = v;
                } else {
                    curm = fmaxf(curm, v);
                }
            }
        }
        if (curx >= 0)
            atomicMax(&i2t[(size_t)(curx * 64 + y) * NI + nn], mono_map(curm));
    }
}

__global__ __launch_bounds__(256) void fin_kernel(const int* __restrict__ tgt,
                                                  char* __restrict__ ws,
                                                  float* __restrict__ out) {
    int w = blockIdx.x * 4 + (threadIdx.x >> 6);
    int lane = threadIdx.x & 63;
    int x = w >> 6;
    const unsigned* iv = (const unsigned*)(ws + I2T_OFF) + (size_t)w * NI;
    float s = mono_unmap(iv[lane]) + mono_unmap(iv[64 + lane]) + mono_unmap(iv[128 + lane]);
    if (lane < 4) s += mono_unmap(iv[192 + lane]);
    #pragma unroll
    for (int d = 1; d < 64; d <<= 1) s += __shfl_xor(s, d);
    if (lane == 0) {
        float i2tv = s * (1.f / (float)NI);
        float t2is = ((const float*)(ws + T2I_OFF))[w];
        int   nvx  = ((const int*)(ws + NV_OFF))[x];
        float t2iv = t2is / fmaxf((float)nvx, EPS_);
        int tg = tgt[w];
        float mi  = (tg == 1) ? (1.f - i2tv) : fmaxf(i2tv - MARGIN_, 0.f);
        float mtv = (tg == 1) ? (1.f - t2iv) : fmaxf(t2iv - MARGIN_, 0.f);
        atomicAdd(out, (mi + mtv) * (1.f / 8192.f));
    }
}

// ================= FALLBACK PATH (f32 VALU, known-correct) =================

__global__ __launch_bounds__(64) void prep0_kernel(const int* __restrict__ pm,
                                                   int* __restrict__ wsi,
                                                   float* __restrict__ out) {
    int x = threadIdx.x;
    if (x == 0) out[0] = 0.f;
    if (x >= B_) return;
    const int* row = pm + x * TTXT;
    int lastz = -1;
    for (int t = 0; t < TTXT; ++t) if (row[t] == 0) lastz = t;
    int eos = (lastz >= 0) ? lastz : 0;
    int nv = 0;
    int* vv = wsi + 64 + x * MT;
    for (int t = 1; t < TTXT; ++t) {
        int v = row[t];
        if (t == eos) v = 1;
        if (v == 0) vv[nv++] = t - 1;
    }
    wsi[x] = nv;
}

__global__ __launch_bounds__(256) void sim0_kernel(const float* __restrict__ img,
                                                   const float* __restrict__ txt,
                                                   const int* __restrict__ tgt,
                                                   const int* __restrict__ wsi,
                                                   float* __restrict__ out)
{
    const int bid = blockIdx.x;
    const int x = bid & 63;
    const int y = bid >> 6;
    const int tid = threadIdx.x;
    const int w = tid >> 6;
    const int c = tid & 63;

    __shared__ float sA[MT][DC];
    __shared__ float sB[NI][DC + 4];
    __shared__ float red[4 * 256];
    __shared__ float wred[8];

    const int nv = wsi[x];
    const int* vv = wsi + 64 + x * MT;

    const float* timg = img + (size_t)y * TIMG * DDIM + DDIM;
    const float* ttxt = txt + (size_t)x * TTXT * DDIM + DDIM;

    float acc[16][4];
    #pragma unroll
    for (int v = 0; v < 16; ++v)
        #pragma unroll
        for (int u = 0; u < 4; ++u) acc[v][u] = 0.f;

    for (int dc = 0; dc < DDIM; dc += DC) {
        __syncthreads();
        for (int r = tid; r < NI * 4; r += 256) {
            int row = r >> 2, seg = r & 3;
            float4 vsrc = *reinterpret_cast<const float4*>(
                timg + (size_t)row * DDIM + dc + seg * 4);
            *reinterpret_cast<float4*>(&sB[row][seg * 4]) = vsrc;
        }
        if (tid < nv * 4) {
            int j = tid >> 2, seg = tid & 3;
            int t = vv[j];
            float4 vsrc = *reinterpret_cast<const float4*>(
                ttxt + (size_t)t * DDIM + dc + seg * 4);
            *reinterpret_cast<float4*>(&sA[j][seg * 4]) = vsrc;
        }
        __syncthreads();
        #pragma unroll
        for (int ds = 0; ds < 4; ++ds) {
            float4 b0 = *reinterpret_cast<const float4*>(&sB[c][ds * 4]);
            float4 b1 = *reinterpret_cast<const float4*>(&sB[c + 64][ds * 4]);
            float4 b2 = *reinterpret_cast<const float4*>(&sB[c + 128][ds * 4]);
            float4 b3 = *reinterpret_cast<const float4*>(&sB[(c + 192 < NI) ? (c + 192) : (NI - 1)][ds * 4]);
            #pragma unroll
            for (int v = 0; v < 16; ++v) {
                int t = 4 * v + w;
                if (t < nv) {
                    float4 a = *reinterpret_cast<const float4*>(&sA[t][ds * 4]);
                    acc[v][0] += a.x * b0.x + a.y * b0.y + a.z * b0.z + a.w * b0.w;
                    acc[v][1] += a.x * b1.x + a.y * b1.y + a.z * b1.z + a.w * b1.w;
                    acc[v][2] += a.x * b2.x + a.y * b2.y + a.z * b2.z + a.w * b2.w;
                    acc[v][3] += a.x * b3.x + a.y * b3.y + a.z * b3.z + a.w * b3.w;
                }
            }
        }
    }

    float tsum = 0.f;
    float cmax[4] = {-FLT_MAX, -FLT_MAX, -FLT_MAX, -FLT_MAX};
    #pragma unroll
    for (int v = 0; v < 16; ++v) {
        int t = 4 * v + w;
        if (t < nv) {
            float r = -FLT_MAX;
            #pragma unroll
            for (int u = 0; u < 4; ++u) {
                int i = c + 64 * u;
                if (i < NI) {
                    float val = acc[v][u];
                    r = fmaxf(r, val);
                    cmax[u] = fmaxf(cmax[u], val);
                }
            }
            #pragma unroll
            for (int off = 1; off < 64; off <<= 1)
                r = fmaxf(r, __shfl_xor(r, off));
            tsum += r;
        }
    }

    __syncthreads();
    #pragma unroll
    for (int u = 0; u < 4; ++u)
        red[w * 256 + c + 64 * u] = cmax[u];
    if (c == 0) wred[w] = tsum;
    __syncthreads();

    float cm = 0.f;
    if (tid < NI) {
        float m0 = fmaxf(red[tid], red[256 + tid]);
        float m1 = fmaxf(red[512 + tid], red[768 + tid]);
        cm = fmaxf(m0, m1);
    }
    float s = cm;
    #pragma unroll
    for (int off = 1; off < 64; off <<= 1)
        s += __shfl_xor(s, off);
    if (c == 0) wred[4 + w] = s;
    __syncthreads();

    if (tid == 0) {
        float rowsum = wred[0] + wred[1] + wred[2] + wred[3];
        float colsum = wred[4] + wred[5] + wred[6] + wred[7];
        float t2i = rowsum / fmaxf((float)nv, EPS_);
        float i2t = colsum * (1.f / (float)NI);
        int tg = tgt[x * 64 + y];
        float mi = (tg == 1) ? (1.f - i2t) : fmaxf(i2t - MARGIN_, 0.f);
        float mt = (tg == 1) ? (1.f - t2i) : fmaxf(t2i - MARGIN_, 0.f);
        atomicAdd(out, (mi + mt) * (1.f / 8192.f));
    }
}

// ================= launcher =================

extern "C" void kernel_launch(void* const* d_in, const int* in_sizes, int n_in,
                              void* d_out, int out_size, void* d_ws, size_t ws_size,
                              hipStream_t stream) {
    const float* img = (const float*)d_in[0];
    const float* txt = (const float*)d_in[1];
    const int*   pm  = (const int*)d_in[2];
    const int*   tgt = (const int*)d_in[3];
    float* out = (float*)d_out;

    if (ws_size >= (size_t)WS_NEEDED) {
        char* wsc = (char*)d_ws;
        hipLaunchKernelGGL(prep_kernel, dim3(1),    dim3(64),  0, stream, pm, wsc);
        hipLaunchKernelGGL(conv_kernel, dim3(2513), dim3(256), 0, stream, img, txt, wsc, out);
        hipLaunchKernelGGL(gemm_kernel, dim3(1024), dim3(512), 0, stream, wsc);
        hipLaunchKernelGGL(fin_kernel,  dim3(1024), dim3(256), 0, stream, tgt, wsc, out);
    } else {
        int* wsi = (int*)d_ws;
        hipLaunchKernelGGL(prep0_kernel, dim3(1),    dim3(64),  0, stream, pm, wsi, out);
        hipLaunchKernelGGL(sim0_kernel,  dim3(4096), dim3(256), 0, stream,
                           img, txt, tgt, wsi, out);
    }
}

// Round 5
// 253.938 us; speedup vs baseline: 5.4543x; 1.2512x over previous
//
#include <hip/hip_runtime.h>
#include <float.h>
#include <stdint.h>

#define B_      64
#define TTXT    64
#define TIMG    197
#define DDIM    768
#define MT      63
#define NI      196
#define NPAD    224
#define DC      16
#define MARGIN_ 0.5f
#define EPS_    1e-6f

// ---- ws byte offsets ----
#define META_OFF   0u          // int meta[16]; meta[0] = R
#define NV_OFF     64u         // int nv[64]
#define ROWSRC_OFF 320u        // int rowsrc[4096]
#define ROWX_OFF   16704u      // int rowx[4096]
#define T2I_OFF    33088u      // float t2i_sum[4096]
#define I2T_OFF    49472u      // uint i2t_part[64*64*196]
// A image: [4096 rows][24 chunks][8 slots][16B] (3072 B/row), swizzle baked
#define AIMG_OFF   3260736u
// B image: [64*224 rows][24 chunks][8 slots][16B]
#define BIMG_OFF   15843648u
#define WS_NEEDED  59883840u
// fin partials reuse the A-image region (dead after gemm)
#define PART_OFF   AIMG_OFF

typedef _Float16 f16x8 __attribute__((ext_vector_type(8)));
typedef float    f32x4 __attribute__((ext_vector_type(4)));

__device__ __forceinline__ unsigned mono_map(float v) {
    unsigned b = __float_as_uint(v);
    return (b & 0x80000000u) ? ~b : (b | 0x80000000u);
}
__device__ __forceinline__ float mono_unmap(unsigned u) {
    unsigned b = (u & 0x80000000u) ? (u & 0x7fffffffu) : ~u;
    return __uint_as_float(b);
}

__device__ __forceinline__ void async_ld16(const void* g, void* l) {
    __builtin_amdgcn_global_load_lds((const __attribute__((address_space(1))) void*)g,
                                     (__attribute__((address_space(3))) void*)l,
                                     16, 0, 0);
}

// ================= FAST PATH =================

__global__ __launch_bounds__(64) void prep_kernel(const int* __restrict__ pm,
                                                  char* __restrict__ ws) {
    int x = threadIdx.x;
    int* meta   = (int*)(ws + META_OFF);
    int* nv     = (int*)(ws + NV_OFF);
    int* rowsrc = (int*)(ws + ROWSRC_OFF);
    int* rowx   = (int*)(ws + ROWX_OFF);
    const int* row = pm + x * TTXT;
    int lastz = -1;
    for (int t = 0; t < TTXT; ++t) if (row[t] == 0) lastz = t;
    int eos = (lastz >= 0) ? lastz : 0;
    int cnt = 0; int loc[63];
    for (int t = 1; t < TTXT; ++t) {
        int v = row[t]; if (t == eos) v = 1;
        if (v == 0) loc[cnt++] = t;
    }
    int s = cnt;
    for (int d = 1; d < 64; d <<= 1) { int o = __shfl_up(s, d); if (x >= d) s += o; }
    int off = s - cnt;
    for (int j = 0; j < cnt; ++j) {
        rowsrc[off + j] = (x * TTXT + loc[j]) * DDIM;
        rowx[off + j] = x;
    }
    nv[x] = cnt;
    if (x == 63) meta[0] = off + cnt;    // R
}

// conv: swizzled hi/lo chunk images + init of reduction buffers.
// thread = (row, kc, dest-slot) -> write addr = base + gid*16 (fully linear).
// source slot sp = s ^ (row&7); group = sp&3 (32B of the kc's 128B); plane = sp>>2.
// grid 14609: [0,3072) A, [3072,13824) B, [13824,14608) i2t init, 14608 t2i init
__global__ __launch_bounds__(256) void conv_kernel(const float* __restrict__ img,
                                                   const float* __restrict__ txt,
                                                   char* __restrict__ ws) {
    const int bid = blockIdx.x, tid = threadIdx.x;
    if (bid < 3072) {                              // ---- A image: 4096 rows x 24 kc x 8 slots
        int gid = bid * 256 + tid;                 // = gr*192 + kc*8 + s
        int s  = gid & 7;
        int kc = (gid >> 3) % 24;
        int gr = gid / 192;
        const int R = *(const int*)(ws + META_OFF);
        int sp = s ^ (gr & 7);
        f16x8 v = 0;
        if (gr < R) {
            const int* rowsrc = (const int*)(ws + ROWSRC_OFF);
            const float* src = txt + rowsrc[gr] + kc * 32 + (sp & 3) * 8;
            float4 f0 = ((const float4*)src)[0];
            float4 f1 = ((const float4*)src)[1];
            float fv[8] = {f0.x, f0.y, f0.z, f0.w, f1.x, f1.y, f1.z, f1.w};
            bool lo = (sp & 4) != 0;
            #pragma unroll
            for (int j = 0; j < 8; ++j) {
                float fx = fv[j];
                _Float16 hh = (_Float16)fx;
                v[j] = lo ? (_Float16)(fx - (float)hh) : hh;
            }
        }
        *(f16x8*)(ws + AIMG_OFF + (size_t)gid * 16) = v;
    } else if (bid < 13824) {                      // ---- B image: 14336 rows x 24 kc x 8 slots
        int gid = (bid - 3072) * 256 + tid;        // = rr*192 + kc*8 + s
        int s  = gid & 7;
        int kc = (gid >> 3) % 24;
        int rr = gid / 192;
        int y = rr / NPAD, i = rr % NPAD;
        int sp = s ^ (rr & 7);                     // NPAD%8==0 -> rr&7 == i&7
        f16x8 v = 0;
        if (i < NI) {
            const float* src = img + (size_t)(y * TIMG + i + 1) * DDIM + kc * 32 + (sp & 3) * 8;
            float4 f0 = ((const float4*)src)[0];
            float4 f1 = ((const float4*)src)[1];
            float fv[8] = {f0.x, f0.y, f0.z, f0.w, f1.x, f1.y, f1.z, f1.w};
            bool lo = (sp & 4) != 0;
            #pragma unroll
            for (int j = 0; j < 8; ++j) {
                float fx = fv[j];
                _Float16 hh = (_Float16)fx;
                v[j] = lo ? (_Float16)(fx - (float)hh) : hh;
            }
        }
        *(f16x8*)(ws + BIMG_OFF + (size_t)gid * 16) = v;
    } else if (bid < 14608) {                      // ---- i2t init (200704 uint4)
        int gid = (bid - 13824) * 256 + tid;
        uint4 v = make_uint4(0x00800000u, 0x00800000u, 0x00800000u, 0x00800000u);
        ((uint4*)(ws + I2T_OFF))[gid] = v;         // mono(-FLT_MAX)
    } else {                                       // ---- t2i init (1024 uint4)
        uint4 z = make_uint4(0u, 0u, 0u, 0u);
        #pragma unroll
        for (int j = 0; j < 4; ++j)
            ((uint4*)(ws + T2I_OFF))[tid * 4 + j] = z;
    }
}

// gemm: grid 1024 = 16 m-tiles(256) x 64 y; 512 threads (8 waves, 4x2 over 256x224)
// merged 3-pass (hh, hl, lh), double-buffered LDS, global_load_lds staging,
// 2-phase pipeline: prefetch chunk k+1 issued before compute of chunk k.
__global__ __launch_bounds__(512, 2) void gemm_kernel(char* __restrict__ ws) {
    const int bid = blockIdx.x;
    const int swz = (bid & 7) * 128 + (bid >> 3);   // XCD-chunked, bijective (1024%8==0)
    const int mt  = swz & 15;                       // mt fastest within XCD chunk
    const int y   = swz >> 4;
    const int R = *(const int*)(ws + META_OFF);
    const int m_base = mt * 256;
    if (m_base >= R) return;

    const int tid = threadIdx.x;
    const int wid = tid >> 6, lane = tid & 63;
    const int c = lane & 15, g = lane >> 4;
    const int wm = wid >> 1, wn = wid & 1;

    __shared__ __align__(16) unsigned char lds[122880];  // 2 x (A 32K + B 28K)

    f32x4 acc[4][7];
    #pragma unroll
    for (int m = 0; m < 4; ++m)
        #pragma unroll
        for (int n = 0; n < 7; ++n) acc[m][n] = 0.f;

    const char* Abp = ws + AIMG_OFF + (size_t)m_base * 3072;
    const char* Bbp = ws + BIMG_OFF + (size_t)(y * NPAD) * 3072;
    const char* ga[4]; const char* gb[4];
    #pragma unroll
    for (int i = 0; i < 4; ++i) { int u = i * 512 + tid; ga[i] = Abp + (u >> 3) * 3072 + (u & 7) * 16; }
    #pragma unroll
    for (int i = 0; i < 4; ++i) { int u = i * 512 + tid; gb[i] = Bbp + (u >> 3) * 3072 + (u & 7) * 16; }

    auto STAGE = [&](int buf, int kc) {
        unsigned char* base = lds + buf * 61440;
        const int ko = kc * 128;
        #pragma unroll
        for (int i = 0; i < 4; ++i)
            async_ld16(ga[i] + ko, base + i * 8192 + wid * 1024);
        #pragma unroll
        for (int i = 0; i < 3; ++i)
            async_ld16(gb[i] + ko, base + 32768 + i * 8192 + wid * 1024);
        if (wid < 4)
            async_ld16(gb[3] + ko, base + 32768 + 24576 + wid * 1024);
    };

    int aofh[4], aofl[4], bofh[7], bofl[7];
    #pragma unroll
    for (int m = 0; m < 4; ++m) {
        int r = wm * 64 + m * 16 + c;
        aofh[m] = r * 128 + ((g ^ (r & 7)) << 4);
        aofl[m] = r * 128 + (((4 | g) ^ (r & 7)) << 4);
    }
    #pragma unroll
    for (int n = 0; n < 7; ++n) {
        int i = wn * 112 + n * 16 + c;
        bofh[n] = 32768 + i * 128 + ((g ^ (i & 7)) << 4);
        bofl[n] = 32768 + i * 128 + (((4 | g) ^ (i & 7)) << 4);
    }

    STAGE(0, 0);
    __syncthreads();

    #pragma unroll 2
    for (int kc = 0; kc < 24; ++kc) {
        const int cur = kc & 1;
        if (kc < 23) STAGE(cur ^ 1, kc + 1);         // prefetch next chunk (in flight)
        const unsigned char* Ab = lds + cur * 61440;
        f16x8 ah[4], bh[7];
        #pragma unroll
        for (int m = 0; m < 4; ++m) ah[m] = *(const f16x8*)(Ab + aofh[m]);
        #pragma unroll
        for (int n = 0; n < 7; ++n) bh[n] = *(const f16x8*)(Ab + bofh[n]);
        #pragma unroll
        for (int m = 0; m < 4; ++m)
            #pragma unroll
            for (int n = 0; n < 7; ++n)
                acc[m][n] = __builtin_amdgcn_mfma_f32_16x16x32_f16(ah[m], bh[n], acc[m][n], 0, 0, 0);
        {
            f16x8 bl[7];
            #pragma unroll
            for (int n = 0; n < 7; ++n) bl[n] = *(const f16x8*)(Ab + bofl[n]);
            #pragma unroll
            for (int m = 0; m < 4; ++m)
                #pragma unroll
                for (int n = 0; n < 7; ++n)
                    acc[m][n] = __builtin_amdgcn_mfma_f32_16x16x32_f16(ah[m], bl[n], acc[m][n], 0, 0, 0);
        }
        {
            f16x8 al[4];
            #pragma unroll
            for (int m = 0; m < 4; ++m) al[m] = *(const f16x8*)(Ab + aofl[m]);
            #pragma unroll
            for (int m = 0; m < 4; ++m)
                #pragma unroll
                for (int n = 0; n < 7; ++n)
                    acc[m][n] = __builtin_amdgcn_mfma_f32_16x16x32_f16(al[m], bh[n], acc[m][n], 0, 0, 0);
        }
        __syncthreads();
    }

    // ---- epilogue ----
    float* rowmax2 = (float*)lds;            // [2][256]
    int*   rowxl   = (int*)(lds + 2048);     // [256]
    const int* rowx = (const int*)(ws + ROWX_OFF);
    if (tid < 256) {
        int gr = m_base + tid;
        rowxl[tid] = (gr < R) ? rowx[gr] : -1;
    }
    // D layout: m = wm*64 + m_i*16 + g*4 + r ; n = wn*112 + n_i*16 + c
    #pragma unroll
    for (int m = 0; m < 4; ++m) {
        #pragma unroll
        for (int r = 0; r < 4; ++r) {
            float v = -FLT_MAX;
            #pragma unroll
            for (int n = 0; n < 7; ++n) {
                int nn = wn * 112 + n * 16 + c;
                if (nn < NI) v = fmaxf(v, acc[m][n][r]);
            }
            #pragma unroll
            for (int d = 1; d < 16; d <<= 1) v = fmaxf(v, __shfl_xor(v, d));
            if (c == 0) rowmax2[wn * 256 + wm * 64 + m * 16 + g * 4 + r] = v;
        }
    }
    __syncthreads();
    if (tid < 256) {
        int gr = m_base + tid;
        if (gr < R) {
            float rm = fmaxf(rowmax2[tid], rowmax2[256 + tid]);
            atomicAdd((float*)(ws + T2I_OFF) + rowxl[tid] * 64 + y, rm);
        }
    }
    int xr[4][4];
    #pragma unroll
    for (int m = 0; m < 4; ++m)
        #pragma unroll
        for (int r = 0; r < 4; ++r)
            xr[m][r] = rowxl[wm * 64 + m * 16 + g * 4 + r];

    unsigned* i2t = (unsigned*)(ws + I2T_OFF);
    #pragma unroll
    for (int n = 0; n < 7; ++n) {
        int nn = wn * 112 + n * 16 + c;
        if (nn >= NI) continue;
        int curx = -1; float curm = 0.f;
        #pragma unroll
        for (int m = 0; m < 4; ++m) {
            #pragma unroll
            for (int r = 0; r < 4; ++r) {
                int xv = xr[m][r];
                float v = acc[m][n][r];
                if (xv != curx) {
                    if (curx >= 0)
                        atomicMax(&i2t[(size_t)(curx * 64 + y) * NI + nn], mono_map(curm));
                    curx = xv; curm = v;
                } else {
                    curm = fmaxf(curm, v);
                }
            }
        }
        if (curx >= 0)
            atomicMax(&i2t[(size_t)(curx * 64 + y) * NI + nn], mono_map(curm));
    }
}

// fin: one (x,y) per wave; block partial -> ws (NO atomics)
__global__ __launch_bounds__(256) void fin_kernel(const int* __restrict__ tgt,
                                                  char* __restrict__ ws) {
    int w = blockIdx.x * 4 + (threadIdx.x >> 6);
    int lane = threadIdx.x & 63;
    int wid = threadIdx.x >> 6;
    int x = w >> 6;
    const unsigned* iv = (const unsigned*)(ws + I2T_OFF) + (size_t)w * NI;
    float s = mono_unmap(iv[lane]) + mono_unmap(iv[64 + lane]) + mono_unmap(iv[128 + lane]);
    if (lane < 4) s += mono_unmap(iv[192 + lane]);
    #pragma unroll
    for (int d = 1; d < 64; d <<= 1) s += __shfl_xor(s, d);
    __shared__ float p4[4];
    if (lane == 0) {
        float i2tv = s * (1.f / (float)NI);
        float t2is = ((const float*)(ws + T2I_OFF))[w];
        int   nvx  = ((const int*)(ws + NV_OFF))[x];
        float t2iv = t2is / fmaxf((float)nvx, EPS_);
        int tg = tgt[w];
        float mi  = (tg == 1) ? (1.f - i2tv) : fmaxf(i2tv - MARGIN_, 0.f);
        float mtv = (tg == 1) ? (1.f - t2iv) : fmaxf(t2iv - MARGIN_, 0.f);
        p4[wid] = mi + mtv;
    }
    __syncthreads();
    if (threadIdx.x == 0)
        ((float*)(ws + PART_OFF))[blockIdx.x] =
            (p4[0] + p4[1] + p4[2] + p4[3]) * (1.f / 8192.f);
}

// final: 1 block reduces 1024 partials -> out[0] (plain store, no atomics)
__global__ __launch_bounds__(256) void final_kernel(char* __restrict__ ws,
                                                    float* __restrict__ out) {
    const float* part = (const float*)(ws + PART_OFF);
    int tid = threadIdx.x;
    float v = part[tid] + part[tid + 256] + part[tid + 512] + part[tid + 768];
    #pragma unroll
    for (int d = 1; d < 64; d <<= 1) v += __shfl_xor(v, d);
    __shared__ float p4[4];
    if ((tid & 63) == 0) p4[tid >> 6] = v;
    __syncthreads();
    if (tid == 0) out[0] = p4[0] + p4[1] + p4[2] + p4[3];
}

// ================= FALLBACK PATH (f32 VALU, known-correct) =================

__global__ __launch_bounds__(64) void prep0_kernel(const int* __restrict__ pm,
                                                   int* __restrict__ wsi,
                                                   float* __restrict__ out) {
    int x = threadIdx.x;
    if (x == 0) out[0] = 0.f;
    if (x >= B_) return;
    const int* row = pm + x * TTXT;
    int lastz = -1;
    for (int t = 0; t < TTXT; ++t) if (row[t] == 0) lastz = t;
    int eos = (lastz >= 0) ? lastz : 0;
    int nv = 0;
    int* vv = wsi + 64 + x * MT;
    for (int t = 1; t < TTXT; ++t) {
        int v = row[t];
        if (t == eos) v = 1;
        if (v == 0) vv[nv++] = t - 1;
    }
    wsi[x] = nv;
}

__global__ __launch_bounds__(256) void sim0_kernel(const float* __restrict__ img,
                                                   const float* __restrict__ txt,
                                                   const int* __restrict__ tgt,
                                                   const int* __restrict__ wsi,
                                                   float* __restrict__ out)
{
    const int bid = blockIdx.x;
    const int x = bid & 63;
    const int y = bid >> 6;
    const int tid = threadIdx.x;
    const int w = tid >> 6;
    const int c = tid & 63;

    __shared__ float sA[MT][DC];
    __shared__ float sB[NI][DC + 4];
    __shared__ float red[4 * 256];
    __shared__ float wred[8];

    const int nv = wsi[x];
    const int* vv = wsi + 64 + x * MT;

    const float* timg = img + (size_t)y * TIMG * DDIM + DDIM;
    const float* ttxt = txt + (size_t)x * TTXT * DDIM + DDIM;

    float acc[16][4];
    #pragma unroll
    for (int v = 0; v < 16; ++v)
        #pragma unroll
        for (int u = 0; u < 4; ++u) acc[v][u] = 0.f;

    for (int dc = 0; dc < DDIM; dc += DC) {
        __syncthreads();
        for (int r = tid; r < NI * 4; r += 256) {
            int row = r >> 2, seg = r & 3;
            float4 vsrc = *reinterpret_cast<const float4*>(
                timg + (size_t)row * DDIM + dc + seg * 4);
            *reinterpret_cast<float4*>(&sB[row][seg * 4]) = vsrc;
        }
        if (tid < nv * 4) {
            int j = tid >> 2, seg = tid & 3;
            int t = vv[j];
            float4 vsrc = *reinterpret_cast<const float4*>(
                ttxt + (size_t)t * DDIM + dc + seg * 4);
            *reinterpret_cast<float4*>(&sA[j][seg * 4]) = vsrc;
        }
        __syncthreads();
        #pragma unroll
        for (int ds = 0; ds < 4; ++ds) {
            float4 b0 = *reinterpret_cast<const float4*>(&sB[c][ds * 4]);
            float4 b1 = *reinterpret_cast<const float4*>(&sB[c + 64][ds * 4]);
            float4 b2 = *reinterpret_cast<const float4*>(&sB[c + 128][ds * 4]);
            float4 b3 = *reinterpret_cast<const float4*>(&sB[(c + 192 < NI) ? (c + 192) : (NI - 1)][ds * 4]);
            #pragma unroll
            for (int v = 0; v < 16; ++v) {
                int t = 4 * v + w;
                if (t < nv) {
                    float4 a = *reinterpret_cast<const float4*>(&sA[t][ds * 4]);
                    acc[v][0] += a.x * b0.x + a.y * b0.y + a.z * b0.z + a.w * b0.w;
                    acc[v][1] += a.x * b1.x + a.y * b1.y + a.z * b1.z + a.w * b1.w;
                    acc[v][2] += a.x * b2.x + a.y * b2.y + a.z * b2.z + a.w * b2.w;
                    acc[v][3] += a.x * b3.x + a.y * b3.y + a.z * b3.z + a.w * b3.w;
                }
            }
        }
    }

    float tsum = 0.f;
    float cmax[4] = {-FLT_MAX, -FLT_MAX, -FLT_MAX, -FLT_MAX};
    #pragma unroll
    for (int v = 0; v < 16; ++v) {
        int t = 4 * v + w;
        if (t < nv) {
            float r = -FLT_MAX;
            #pragma unroll
            for (int u = 0; u < 4; ++u) {
                int i = c + 64 * u;
                if (i < NI) {
                    float val = acc[v][u];
                    r = fmaxf(r, val);
                    cmax[u] = fmaxf(cmax[u], val);
                }
            }
            #pragma unroll
            for (int off = 1; off < 64; off <<= 1)
                r = fmaxf(r, __shfl_xor(r, off));
            tsum += r;
        }
    }

    __syncthreads();
    #pragma unroll
    for (int u = 0; u < 4; ++u)
        red[w * 256 + c + 64 * u] = cmax[u];
    if (c == 0) wred[w] = tsum;
    __syncthreads();

    float cm = 0.f;
    if (tid < NI) {
        float m0 = fmaxf(red[tid], red[256 + tid]);
        float m1 = fmaxf(red[512 + tid], red[768 + tid]);
        cm = fmaxf(m0, m1);
    }
    float s = cm;
    #pragma unroll
    for (int off = 1; off < 64; off <<= 1)
        s += __shfl_xor(s, off);
    if (c == 0) wred[4 + w] = s;
    __syncthreads();

    if (tid == 0) {
        float rowsum = wred[0] + wred[1] + wred[2] + wred[3];
        float colsum = wred[4] + wred[5] + wred[6] + wred[7];
        float t2i = rowsum / fmaxf((float)nv, EPS_);
        float i2t = colsum * (1.f / (float)NI);
        int tg = tgt[x * 64 + y];
        float mi = (tg == 1) ? (1.f - i2t) : fmaxf(i2t - MARGIN_, 0.f);
        float mt = (tg == 1) ? (1.f - t2i) : fmaxf(t2i - MARGIN_, 0.f);
        atomicAdd(out, (mi + mt) * (1.f / 8192.f));
    }
}

// ================= launcher =================

extern "C" void kernel_launch(void* const* d_in, const int* in_sizes, int n_in,
                              void* d_out, int out_size, void* d_ws, size_t ws_size,
                              hipStream_t stream) {
    const float* img = (const float*)d_in[0];
    const float* txt = (const float*)d_in[1];
    const int*   pm  = (const int*)d_in[2];
    const int*   tgt = (const int*)d_in[3];
    float* out = (float*)d_out;

    if (ws_size >= (size_t)WS_NEEDED) {
        char* wsc = (char*)d_ws;
        hipLaunchKernelGGL(prep_kernel,  dim3(1),     dim3(64),  0, stream, pm, wsc);
        hipLaunchKernelGGL(conv_kernel,  dim3(14609), dim3(256), 0, stream, img, txt, wsc);
        hipLaunchKernelGGL(gemm_kernel,  dim3(1024),  dim3(512), 0, stream, wsc);
        hipLaunchKernelGGL(fin_kernel,   dim3(1024),  dim3(256), 0, stream, tgt, wsc);
        hipLaunchKernelGGL(final_kernel, dim3(1),     dim3(256), 0, stream, wsc, out);
    } else {
        int* wsi = (int*)d_ws;
        hipLaunchKernelGGL(prep0_kernel, dim3(1),    dim3(64),  0, stream, pm, wsi, out);
        hipLaunchKernelGGL(sim0_kernel,  dim3(4096), dim3(256), 0, stream,
                           img, txt, tgt, wsi, out);
    }
}